// Round 4
// baseline (591.602 us; speedup 1.0000x reference)
//
#include <hip/hip_runtime.h>
#include <hip/hip_bf16.h>

#define TT 2048
#define BB 512
#define HH 32
#define NPAIR (TT * BB)
#define PSTRIDE (BB * HH)   // floats per t-slice of P = 16384
#define EPS 32              // steps per LDS epoch
#define NEP (TT / EPS)      // 64 epochs

// tanh(u) = 1 - 2/(1+e^{2u}); exact at both saturations.
__device__ __forceinline__ float fast_tanh(float u) {
    float e = exp2f(u * 2.88539008177792681f);          // e^{2u} via v_exp_f32
    return 1.0f - 2.0f * __builtin_amdgcn_rcpf(e + 1.0f);
}

__device__ __forceinline__ float bcast(float v, int srclane) {
    return __uint_as_float(__builtin_amdgcn_readlane(__float_as_uint(v), srclane));
}

// ---------------- Pass 1: P[t][row][j] = b[j] + emb[x[t,row]] @ Wx[:,j] ----------------
// 2 pairs fully in flight per 32-lane group (idx int2 -> 16 gather loads -> 64 FMA).
// 4 waves/SIMD (VGPR<=128) gives the TLP to hide the idx->gather chain.
__global__ __launch_bounds__(256, 4) void precompute_v4(
        const int* __restrict__ x, const float* __restrict__ emb,
        const float* __restrict__ W_rnn, const float* __restrict__ b_rnn,
        float* __restrict__ P) {
    const int lane = threadIdx.x & 31;
    const int g    = (blockIdx.x * blockDim.x + threadIdx.x) >> 5;

    float wx[32];
#pragma unroll
    for (int k = 0; k < 32; ++k) wx[k] = W_rnn[k * HH + lane];
    const float bj = b_rnn[lane];

    const int pair0 = g * 2;                       // NPAIR/2 groups exactly
    const int2 iv = *(const int2*)(x + pair0);     // broadcast within group

    float4 e0[8], e1[8];
    {
        const float4* ep0 = (const float4*)(emb + (size_t)iv.x * HH);
        const float4* ep1 = (const float4*)(emb + (size_t)iv.y * HH);
#pragma unroll
        for (int q = 0; q < 8; ++q) { e0[q] = ep0[q]; e1[q] = ep1[q]; }
    }
    float a0 = bj, a1 = 0.f, a2 = 0.f, a3 = 0.f;
    float c0 = bj, c1 = 0.f, c2 = 0.f, c3 = 0.f;
#pragma unroll
    for (int q = 0; q < 8; ++q) {
        a0 = fmaf(e0[q].x, wx[4*q+0], a0);
        a1 = fmaf(e0[q].y, wx[4*q+1], a1);
        a2 = fmaf(e0[q].z, wx[4*q+2], a2);
        a3 = fmaf(e0[q].w, wx[4*q+3], a3);
        c0 = fmaf(e1[q].x, wx[4*q+0], c0);
        c1 = fmaf(e1[q].y, wx[4*q+1], c1);
        c2 = fmaf(e1[q].z, wx[4*q+2], c2);
        c3 = fmaf(e1[q].w, wx[4*q+3], c3);
    }
    P[(size_t)pair0 * HH + lane]       = (a0 + a1) + (a2 + a3);
    P[(size_t)(pair0 + 1) * HH + lane] = (c0 + c1) + (c2 + c3);
}

// ---------------- Pass 2: sequential scan, 1 row/wave, LDS-staged P, readlane bcast ----
// P staged per-epoch (32 steps = 4 KB) through a register double buffer: epoch e+2 is
// bulk-loaded into regs while consuming epoch e; at the boundary the regs (now 1 epoch
// old -> implicit vmcnt wait is free) are ds_written. Per-step: 1 ds_read_b32 (prefetch
// ring, depth 4) + 32 readlane + 32 FMA + tanh. No per-step global load => no per-step
// memory-latency serialization.
__global__ __launch_bounds__(64) void rnn_seq_v4(
        const float* __restrict__ P, const float* __restrict__ W_rnn,
        const float* __restrict__ W_cls, const float* __restrict__ b_cls,
        float* __restrict__ out) {
    const int l   = threadIdx.x;
    const int jj  = l & 31;
    const int row = blockIdx.x;

    float wh[32];
#pragma unroll
    for (int k = 0; k < 32; ++k) wh[k] = W_rnn[(HH + k) * HH + jj];

    __shared__ __align__(16) float pbuf[2][EPS * HH];   // 2 x 4 KB

    // Staging map: lane l covers (tloc = l>>1, j0 = (l&1)*16): 16 consecutive floats
    // of one t-slice => 4 x dwordx4 global loads + 4 x ds_write_b128.
    const int tloc = l >> 1;
    const int j0   = (l & 1) * 16;
    const float* gbase = P + (size_t)row * HH + j0;
    const int lwoff = tloc * HH + j0;

    float4 r[4];
#pragma unroll
    for (int q = 0; q < 4; ++q)     // preload epoch 0
        r[q] = *(const float4*)(gbase + (size_t)tloc * PSTRIDE + 4 * q);
#pragma unroll
    for (int q = 0; q < 4; ++q)     // commit epoch 0 to slot 0 (one-time full-latency wait)
        *(float4*)&pbuf[0][lwoff + 4 * q] = r[q];
#pragma unroll
    for (int q = 0; q < 4; ++q)     // preload epoch 1
        r[q] = *(const float4*)(gbase + (size_t)(EPS + tloc) * PSTRIDE + 4 * q);

    float h = 0.0f;
    float pr[4];

    for (int e = 0; e < NEP; ++e) {
        const int slot = e & 1;
        // Commit staged regs (epoch e+1) to the other slot; loads are ~1 epoch old.
#pragma unroll
        for (int q = 0; q < 4; ++q)
            *(float4*)&pbuf[slot ^ 1][lwoff + 4 * q] = r[q];
        // Issue bulk loads for epoch e+2 (clamped; redundant reload of last epoch ok).
        int en = e + 2; if (en > NEP - 1) en = NEP - 1;
#pragma unroll
        for (int q = 0; q < 4; ++q)
            r[q] = *(const float4*)(gbase + (size_t)(en * EPS + tloc) * PSTRIDE + 4 * q);

        const float* pb = &pbuf[slot][jj];
#pragma unroll
        for (int d = 0; d < 4; ++d) pr[d] = pb[d * HH];   // prime the p ring

#pragma unroll
        for (int s = 0; s < EPS; ++s) {
            float u0 = pr[s & 3];
            const int sp = (s + 4 < EPS) ? (s + 4) : (EPS - 1);  // static after unroll
            pr[s & 3] = pb[sp * HH];

            float u1 = 0.f, u2 = 0.f, u3 = 0.f, u4 = 0.f, u5 = 0.f, u6 = 0.f, u7 = 0.f;
#pragma unroll
            for (int q = 0; q < 4; ++q) {
                u0 = fmaf(bcast(h, 8*q+0), wh[8*q+0], u0);
                u1 = fmaf(bcast(h, 8*q+1), wh[8*q+1], u1);
                u2 = fmaf(bcast(h, 8*q+2), wh[8*q+2], u2);
                u3 = fmaf(bcast(h, 8*q+3), wh[8*q+3], u3);
                u4 = fmaf(bcast(h, 8*q+4), wh[8*q+4], u4);
                u5 = fmaf(bcast(h, 8*q+5), wh[8*q+5], u5);
                u6 = fmaf(bcast(h, 8*q+6), wh[8*q+6], u6);
                u7 = fmaf(bcast(h, 8*q+7), wh[8*q+7], u7);
            }
            float u = ((u0 + u1) + (u2 + u3)) + ((u4 + u5) + (u6 + u7));
            h = fast_tanh(u);
        }
    }

    // Epilogue: y = h @ W_cls + b_cls (N_CLASS = 5); store from low-half lanes only.
    if (l < 5) {
        float acc = b_cls[l];
#pragma unroll
        for (int k = 0; k < 32; ++k)
            acc = fmaf(bcast(h, k), W_cls[k * 5 + l], acc);
        out[row * 5 + l] = acc;
    }
}

// ---------------- Fallback (R1 fused kernel) for tiny workspace ------------------------
__device__ __forceinline__ float rnn_step_fb(const float4 xt[8], const float wx[32],
                                             const float wh[32], float bj,
                                             float* hrow, int lane) {
    float u0 = 0.f, u1 = 0.f, u2 = 0.f, u3 = 0.f;
#pragma unroll
    for (int q = 0; q < 8; ++q) {
        u0 = fmaf(xt[q].x, wx[4*q+0], u0);
        u1 = fmaf(xt[q].y, wx[4*q+1], u1);
        u2 = fmaf(xt[q].z, wx[4*q+2], u2);
        u3 = fmaf(xt[q].w, wx[4*q+3], u3);
    }
    const float4* hp = (const float4*)hrow;
#pragma unroll
    for (int q = 0; q < 8; ++q) {
        float4 hv = hp[q];
        u0 = fmaf(hv.x, wh[4*q+0], u0);
        u1 = fmaf(hv.y, wh[4*q+1], u1);
        u2 = fmaf(hv.z, wh[4*q+2], u2);
        u3 = fmaf(hv.w, wh[4*q+3], u3);
    }
    float hn = fast_tanh(bj + ((u0 + u1) + (u2 + u3)));
    hrow[lane] = hn;
    return hn;
}

__global__ __launch_bounds__(64) void rnn_seq_kernel(
        const int* __restrict__ x, const float* __restrict__ emb,
        const float* __restrict__ W_rnn, const float* __restrict__ b_rnn,
        const float* __restrict__ W_cls, const float* __restrict__ b_cls,
        float* __restrict__ out) {
    const int lane = threadIdx.x & 31;
    const int grp  = threadIdx.x >> 5;
    const int row  = blockIdx.x * 2 + grp;
    __shared__ float hbuf[2][HH];
    float wx[32], wh[32];
#pragma unroll
    for (int k = 0; k < 32; ++k) {
        wx[k] = W_rnn[k * HH + lane];
        wh[k] = W_rnn[(HH + k) * HH + lane];
    }
    const float bj = b_rnn[lane];
    hbuf[grp][lane] = 0.0f;
    float* hrow = &hbuf[grp][0];
    int i1 = x[1 * BB + row];
    float4 xcur[8], xnxt[8];
    {
        int i0 = x[0 * BB + row];
        const float4* ep = (const float4*)(emb + (size_t)i0 * HH);
#pragma unroll
        for (int q = 0; q < 8; ++q) xcur[q] = ep[q];
    }
    for (int t = 0; t < TT; t += 2) {
        int i2 = x[min(t + 2, TT - 1) * BB + row];
        {
            const float4* ep = (const float4*)(emb + (size_t)i1 * HH);
#pragma unroll
            for (int q = 0; q < 8; ++q) xnxt[q] = ep[q];
        }
        rnn_step_fb(xcur, wx, wh, bj, hrow, lane);
        i1 = x[min(t + 3, TT - 1) * BB + row];
        {
            const float4* ep = (const float4*)(emb + (size_t)i2 * HH);
#pragma unroll
            for (int q = 0; q < 8; ++q) xcur[q] = ep[q];
        }
        rnn_step_fb(xnxt, wx, wh, bj, hrow, lane);
    }
    if (lane < 5) {
        float acc = b_cls[lane];
#pragma unroll
        for (int k = 0; k < 32; ++k)
            acc = fmaf(hrow[k], W_cls[k * 5 + lane], acc);
        out[row * 5 + lane] = acc;
    }
}

extern "C" void kernel_launch(void* const* d_in, const int* in_sizes, int n_in,
                              void* d_out, int out_size, void* d_ws, size_t ws_size,
                              hipStream_t stream) {
    const int*   x     = (const int*)d_in[0];
    const float* emb   = (const float*)d_in[1];
    const float* W_rnn = (const float*)d_in[2];
    const float* b_rnn = (const float*)d_in[3];
    const float* W_cls = (const float*)d_in[4];
    const float* b_cls = (const float*)d_in[5];
    float* out = (float*)d_out;

    const size_t need32 = (size_t)NPAIR * HH * 4;   // 128 MiB
    if (ws_size >= need32) {
        float* P = (float*)d_ws;
        const int pre_blocks = NPAIR / (2 * 8);     // 65536 blocks x 256 thr
        precompute_v4<<<pre_blocks, 256, 0, stream>>>(x, emb, W_rnn, b_rnn, P);
        rnn_seq_v4<<<BB, 64, 0, stream>>>(P, W_rnn, W_cls, b_cls, out);
    } else {
        rnn_seq_kernel<<<BB / 2, 64, 0, stream>>>(x, emb, W_rnn, b_rnn, W_cls, b_cls, out);
    }
}